// Round 1
// baseline (1138.429 us; speedup 1.0000x reference)
//
#include <hip/hip_runtime.h>
#include <stdint.h>
#include <math.h>

#define DIM   1024
#define SEQ   2048
#define BATCH 8

typedef __attribute__((ext_vector_type(8))) short short8;
typedef __attribute__((ext_vector_type(4))) float floatx4;

__device__ __forceinline__ unsigned short f2bf(float f) {
    union { float f; unsigned u; } v; v.f = f;
    unsigned r = v.u + 0x7fffu + ((v.u >> 16) & 1u);
    return (unsigned short)(r >> 16);
}

__device__ __forceinline__ uint2 pack4bf(float a, float b, float c, float d) {
    uint2 r;
    r.x = (unsigned)f2bf(a) | ((unsigned)f2bf(b) << 16);
    r.y = (unsigned)f2bf(c) | ((unsigned)f2bf(d) << 16);
    return r;
}

// out[m,n] = sum_d (X[m,d] + ctx[d]) * W[n,d] + bias[n], output bf16.
// transpose_out=0: out is [B*S, D] row-major. transpose_out=1: out is [B, D, S] (vT).
__global__ __launch_bounds__(256, 2) void proj_kernel(
    const float* __restrict__ X, const float* __restrict__ ctx,
    const float* __restrict__ W, const float* __restrict__ bias,
    unsigned short* __restrict__ out, int transpose_out, int use_ctx)
{
    __shared__ unsigned short As[128 * 40];  // stride 40: 16B-aligned rows, 2-way-max bank alias
    __shared__ unsigned short Bs[128 * 40];

    const int tid  = threadIdx.x;
    const int lane = tid & 63;
    const int wave = tid >> 6;
    const int quad = lane >> 4;
    const int l16  = lane & 15;
    const int wy = wave >> 1, wx = wave & 1;
    const int row0 = blockIdx.x * 128;
    const int col0 = blockIdx.y * 128;

    floatx4 acc[4][4];
#pragma unroll
    for (int i = 0; i < 4; ++i)
#pragma unroll
        for (int j = 0; j < 4; ++j)
            acc[i][j] = (floatx4){0.f, 0.f, 0.f, 0.f};

    const int sr = tid >> 3;         // 0..31
    const int sc = (tid & 7) << 2;   // 0,4,...,28

    for (int k0 = 0; k0 < DIM; k0 += 32) {
        float cx = 0.f, cy = 0.f, cz = 0.f, cw = 0.f;
        if (use_ctx) {
            const float4 cv = *(const float4*)&ctx[k0 + sc];
            cx = cv.x; cy = cv.y; cz = cv.z; cw = cv.w;
        }
#pragma unroll
        for (int p = 0; p < 4; ++p) {
            const int r = sr + p * 32;
            const float4 a = *(const float4*)&X[(size_t)(row0 + r) * DIM + k0 + sc];
            *(uint2*)&As[r * 40 + sc] = pack4bf(a.x + cx, a.y + cy, a.z + cz, a.w + cw);
            const float4 b = *(const float4*)&W[(size_t)(col0 + r) * DIM + k0 + sc];
            *(uint2*)&Bs[r * 40 + sc] = pack4bf(b.x, b.y, b.z, b.w);
        }
        __syncthreads();

        short8 af[4], bfr[4];
#pragma unroll
        for (int t = 0; t < 4; ++t) {
            af[t]  = *(const short8*)&As[(wy * 64 + t * 16 + l16) * 40 + quad * 8];
            bfr[t] = *(const short8*)&Bs[(wx * 64 + t * 16 + l16) * 40 + quad * 8];
        }
#pragma unroll
        for (int mt = 0; mt < 4; ++mt)
#pragma unroll
            for (int nt = 0; nt < 4; ++nt)
                acc[mt][nt] = __builtin_amdgcn_mfma_f32_16x16x32_bf16(
                    af[mt], bfr[nt], acc[mt][nt], 0, 0, 0);
        __syncthreads();
    }

    // epilogue: + bias, store bf16. C/D layout: col = l16, row = quad*4 + reg.
#pragma unroll
    for (int nt = 0; nt < 4; ++nt) {
        const int n = col0 + wx * 64 + nt * 16 + l16;
        const float bz = bias[n];
#pragma unroll
        for (int mt = 0; mt < 4; ++mt) {
            const int mbase = row0 + wy * 64 + mt * 16 + quad * 4;
            const floatx4 a = acc[mt][nt];
            if (!transpose_out) {
#pragma unroll
                for (int rg = 0; rg < 4; ++rg)
                    out[(size_t)(mbase + rg) * DIM + n] = f2bf(a[rg] + bz);
            } else {
                const int bb = mbase >> 11;          // /SEQ
                const int ss = mbase & (SEQ - 1);    // consecutive s for reg 0..3
                *(uint2*)&out[((size_t)bb * DIM + n) * SEQ + ss] =
                    pack4bf(a[0] + bz, a[1] + bz, a[2] + bz, a[3] + bz);
            }
        }
    }
}

// Flash attention, causal, single head, head-dim 1024.
// Block: 256 threads (4 waves). 32 Q-rows per block, Bc=32 keys/iter.
// Waves split D into 4 chunks of 256 (partial QK^T reduce via LDS; PV output cols).
__global__ __launch_bounds__(256, 2) void attn_kernel(
    const unsigned short* __restrict__ Q, const unsigned short* __restrict__ K,
    const unsigned short* __restrict__ VT, float* __restrict__ out)
{
    __shared__ float Sp[4][32][33];
    __shared__ unsigned short Pl[32 * 40];
    __shared__ float mS[32], lS[32], aS[32];

    const int tid  = threadIdx.x;
    const int lane = tid & 63;
    const int wave = tid >> 6;
    const int quad = lane >> 4;
    const int l16  = lane & 15;

    // work-balanced remap: CU gets (q, q+32) whose causal work sums to ~const
    const int f    = blockIdx.x;
    const int by   = f & 7;
    const int qRaw = f >> 3;                                   // 0..63
    const int qb   = (qRaw < 32) ? (2 * qRaw) : (127 - 2 * qRaw);
    const int q0   = qb * 32;

    if (tid < 32) { mS[tid] = -INFINITY; lS[tid] = 0.f; aS[tid] = 0.f; }
    __syncthreads();

    floatx4 o[2][16];
#pragma unroll
    for (int mt = 0; mt < 2; ++mt)
#pragma unroll
        for (int nt = 0; nt < 16; ++nt)
            o[mt][nt] = (floatx4){0.f, 0.f, 0.f, 0.f};

    const int rr = tid >> 3;        // softmax row 0..31
    const int c0 = (tid & 7) << 2;  // softmax col group

    const size_t qrow = (size_t)by * SEQ;
    const size_t vrow = (size_t)by * DIM;

    for (int j = 0; j <= qb; ++j) {
        // ---- QK^T partial over this wave's 256-wide D chunk ----
        floatx4 sp[2][2];
#pragma unroll
        for (int mt = 0; mt < 2; ++mt)
#pragma unroll
            for (int nt = 0; nt < 2; ++nt)
                sp[mt][nt] = (floatx4){0.f, 0.f, 0.f, 0.f};

#pragma unroll
        for (int ks = 0; ks < 8; ++ks) {
            const int koff = wave * 256 + ks * 32 + quad * 8;
            short8 kb[2], qa[2];
#pragma unroll
            for (int nt = 0; nt < 2; ++nt)
                kb[nt] = *(const short8*)&K[(qrow + j * 32 + nt * 16 + l16) * DIM + koff];
#pragma unroll
            for (int mt = 0; mt < 2; ++mt)
                qa[mt] = *(const short8*)&Q[(qrow + q0 + mt * 16 + l16) * DIM + koff];
#pragma unroll
            for (int mt = 0; mt < 2; ++mt)
#pragma unroll
                for (int nt = 0; nt < 2; ++nt)
                    sp[mt][nt] = __builtin_amdgcn_mfma_f32_16x16x32_bf16(
                        qa[mt], kb[nt], sp[mt][nt], 0, 0, 0);
        }
#pragma unroll
        for (int mt = 0; mt < 2; ++mt)
#pragma unroll
            for (int nt = 0; nt < 2; ++nt)
#pragma unroll
                for (int rg = 0; rg < 4; ++rg)
                    Sp[wave][mt * 16 + quad * 4 + rg][nt * 16 + l16] = sp[mt][nt][rg];
        __syncthreads();

        // ---- reduce partials + online softmax (8 threads per row) ----
        float s0, s1, s2, s3;
        {
            const bool diag = (j == qb);
            float t[4];
#pragma unroll
            for (int i = 0; i < 4; ++i) {
                const int c = c0 + i;
                float v = (Sp[0][rr][c] + Sp[1][rr][c] + Sp[2][rr][c] + Sp[3][rr][c]) * 0.03125f;
                if (diag && c > rr) v = -INFINITY;
                t[i] = v;
            }
            s0 = t[0]; s1 = t[1]; s2 = t[2]; s3 = t[3];
        }
        float mx = fmaxf(fmaxf(s0, s1), fmaxf(s2, s3));
#pragma unroll
        for (int off = 1; off < 8; off <<= 1) mx = fmaxf(mx, __shfl_xor(mx, off));
        const float mold = mS[rr];
        const float mnew = fmaxf(mold, mx);
        const float p0 = __expf(s0 - mnew), p1 = __expf(s1 - mnew);
        const float p2 = __expf(s2 - mnew), p3 = __expf(s3 - mnew);
        float rs = p0 + p1 + p2 + p3;
#pragma unroll
        for (int off = 1; off < 8; off <<= 1) rs += __shfl_xor(rs, off);
        const float alpha = __expf(mold - mnew);
        if ((tid & 7) == 0) {
            mS[rr] = mnew;
            lS[rr] = lS[rr] * alpha + rs;
            aS[rr] = alpha;
        }
        *(uint2*)&Pl[rr * 40 + c0] = pack4bf(p0, p1, p2, p3);
        __syncthreads();

        // ---- PV over this wave's 256 output cols ----
        short8 pa[2];
#pragma unroll
        for (int mt = 0; mt < 2; ++mt)
            pa[mt] = *(const short8*)&Pl[(mt * 16 + l16) * 40 + quad * 8];
        float al[2][4];
#pragma unroll
        for (int mt = 0; mt < 2; ++mt)
#pragma unroll
            for (int rg = 0; rg < 4; ++rg)
                al[mt][rg] = aS[mt * 16 + quad * 4 + rg];
#pragma unroll
        for (int mt = 0; mt < 2; ++mt)
#pragma unroll
            for (int nt = 0; nt < 16; ++nt)
#pragma unroll
                for (int rg = 0; rg < 4; ++rg)
                    o[mt][nt][rg] *= al[mt][rg];
#pragma unroll
        for (int nt = 0; nt < 16; ++nt) {
            const short8 vb = *(const short8*)
                &VT[(vrow + wave * 256 + nt * 16 + l16) * SEQ + j * 32 + quad * 8];
#pragma unroll
            for (int mt = 0; mt < 2; ++mt)
                o[mt][nt] = __builtin_amdgcn_mfma_f32_16x16x32_bf16(
                    pa[mt], vb, o[mt][nt], 0, 0, 0);
        }
        // no barrier needed: next iter's Sp writes don't alias Pl/aS, and the
        // post-Sp __syncthreads orders the next reduce-phase writes to Pl/aS/mS/lS.
    }

    float linv[2][4];
#pragma unroll
    for (int mt = 0; mt < 2; ++mt)
#pragma unroll
        for (int rg = 0; rg < 4; ++rg)
            linv[mt][rg] = 1.0f / lS[mt * 16 + quad * 4 + rg];
#pragma unroll
    for (int mt = 0; mt < 2; ++mt)
#pragma unroll
        for (int nt = 0; nt < 16; ++nt)
#pragma unroll
            for (int rg = 0; rg < 4; ++rg)
                out[(qrow + q0 + mt * 16 + quad * 4 + rg) * DIM + wave * 256 + nt * 16 + l16]
                    = o[mt][nt][rg] * linv[mt][rg];
}

extern "C" void kernel_launch(void* const* d_in, const int* in_sizes, int n_in,
                              void* d_out, int out_size, void* d_ws, size_t ws_size,
                              hipStream_t stream) {
    const float* query = (const float*)d_in[0];
    const float* key   = (const float*)d_in[1];
    const float* value = (const float*)d_in[2];
    const float* ctx   = (const float*)d_in[3];
    const float* Wq    = (const float*)d_in[4];
    const float* bq    = (const float*)d_in[5];
    const float* Wk    = (const float*)d_in[6];
    const float* bk    = (const float*)d_in[7];
    const float* Wv    = (const float*)d_in[8];
    const float* bv    = (const float*)d_in[9];

    const size_t BSD = (size_t)BATCH * SEQ * DIM;
    unsigned short* qw = (unsigned short*)d_ws;   // [B,S,D] bf16
    unsigned short* kw = qw + BSD;                // [B,S,D] bf16
    unsigned short* vw = kw + BSD;                // [B,D,S] bf16 (transposed)
    float* out = (float*)d_out;

    const dim3 pg((BATCH * SEQ) / 128, DIM / 128);  // (128, 8)
    const dim3 pb(256);
    proj_kernel<<<pg, pb, 0, stream>>>(query, ctx, Wq, bq, qw, 0, 1);
    proj_kernel<<<pg, pb, 0, stream>>>(key,   ctx, Wk, bk, kw, 0, 1);
    proj_kernel<<<pg, pb, 0, stream>>>(value, ctx, Wv, bv, vw, 1, 0);

    attn_kernel<<<dim3(BATCH * (SEQ / 32)), dim3(256), 0, stream>>>(qw, kw, vw, out);
}